// Round 1
// baseline (1634.878 us; speedup 1.0000x reference)
//
#include <hip/hip_runtime.h>
#include <math.h>

// Mesh encoder: 4x (spiral conv + ELU + sparse pool) + final GEMM.
// VERTS = [65536, 16384, 4096, 1024, 256], SEQ=9, CH=[3,32,64,128,256], B=16.
//
// Fused design: conv+ELU is computed per pooling edge (nnz = 0.75*V_i), so we
// never materialize y_i. Ping-pong pooled activations in d_ws.

#define BATCH 16
#define SEQL 9

// Thread = (edge k, cout co), accumulating BT batches at once.
// Block = COUT * KPB threads (always 256).
template<int CIN, int COUT, int KPB, int BT>
__global__ __launch_bounds__(256)
void conv_pool(const float* __restrict__ x,    // [B, NV, CIN]
               const int* __restrict__ idx,    // [NV, 9]
               const int* __restrict__ row,    // [nnz]
               const int* __restrict__ col,    // [nnz]
               const float* __restrict__ val,  // [nnz]
               const float* __restrict__ W,    // [9*CIN, COUT]
               const float* __restrict__ bias, // [COUT]
               float* __restrict__ out,        // [B, NVOUT, COUT], pre-zeroed
               int NV, int NVOUT, int nnz)
{
    const int co   = threadIdx.x % COUT;
    const int ksub = threadIdx.x / COUT;
    const int k    = blockIdx.x * KPB + ksub;
    if (k >= nnz) return;
    const int b0 = blockIdx.y * BT;

    const int   n = col[k];
    const float v = val[k];
    const int   r = row[k];

    float acc[BT];
#pragma unroll
    for (int t = 0; t < BT; ++t) acc[t] = bias[co];

#pragma unroll
    for (int s = 0; s < SEQL; ++s) {
        const int vi = idx[n * SEQL + s];
        const float* wp = W + (size_t)(s * CIN) * COUT + co;
        const float* xp = x + ((size_t)b0 * NV + vi) * CIN;
        for (int c = 0; c < CIN; ++c) {
            const float w = wp[(size_t)c * COUT];
#pragma unroll
            for (int t = 0; t < BT; ++t) {
                acc[t] = fmaf(xp[(size_t)t * NV * CIN + c], w, acc[t]);
            }
        }
    }

#pragma unroll
    for (int t = 0; t < BT; ++t) {
        float y = acc[t];
        y = (y > 0.0f) ? y : expm1f(y);
        atomicAdd(&out[(((size_t)(b0 + t) * NVOUT) + r) * COUT + co], v * y);
    }
}

// out[b,l] = bf[l]  (init before atomic partial sums)
__global__ void init_out(const float* __restrict__ bf, float* __restrict__ out)
{
    out[blockIdx.x * 256 + threadIdx.x] = bf[threadIdx.x];
}

// Final GEMM: out[b,l] += sum_j x[b,j] * Wf[j,l]; x is [16, 65536].
// Each block handles a 128-wide j-chunk, all 16 b, all 256 l.
__global__ __launch_bounds__(256)
void final_gemm(const float* __restrict__ x,   // [16, 65536]
                const float* __restrict__ Wf,  // [65536, 256]
                float* __restrict__ out)       // [16, 256]
{
    __shared__ float xs[BATCH][128];
    const int j0 = blockIdx.x * 128;
    const int t  = threadIdx.x;

    for (int i = t; i < BATCH * 128; i += 256) {
        const int b = i / 128, j = i % 128;
        xs[b][j] = x[(size_t)b * 65536 + j0 + j];
    }
    __syncthreads();

    const int l = t;
    float acc[BATCH];
#pragma unroll
    for (int b = 0; b < BATCH; ++b) acc[b] = 0.0f;

    for (int j = 0; j < 128; ++j) {
        const float w = Wf[(size_t)(j0 + j) * 256 + l];
#pragma unroll
        for (int b = 0; b < BATCH; ++b) acc[b] = fmaf(xs[b][j], w, acc[b]);
    }

#pragma unroll
    for (int b = 0; b < BATCH; ++b) atomicAdd(&out[b * 256 + l], acc[b]);
}

extern "C" void kernel_launch(void* const* d_in, const int* in_sizes, int n_in,
                              void* d_out, int out_size, void* d_ws, size_t ws_size,
                              hipStream_t stream)
{
    const float* x    = (const float*)d_in[0];
    const int*   idx0 = (const int*)d_in[1];
    const int*   row0 = (const int*)d_in[2];
    const int*   col0 = (const int*)d_in[3];
    const float* val0 = (const float*)d_in[4];
    const float* W0   = (const float*)d_in[5];
    const float* b0   = (const float*)d_in[6];
    const int*   idx1 = (const int*)d_in[7];
    const int*   row1 = (const int*)d_in[8];
    const int*   col1 = (const int*)d_in[9];
    const float* val1 = (const float*)d_in[10];
    const float* W1   = (const float*)d_in[11];
    const float* b1   = (const float*)d_in[12];
    const int*   idx2 = (const int*)d_in[13];
    const int*   row2 = (const int*)d_in[14];
    const int*   col2 = (const int*)d_in[15];
    const float* val2 = (const float*)d_in[16];
    const float* W2   = (const float*)d_in[17];
    const float* b2   = (const float*)d_in[18];
    const int*   idx3 = (const int*)d_in[19];
    const int*   row3 = (const int*)d_in[20];
    const int*   col3 = (const int*)d_in[21];
    const float* val3 = (const float*)d_in[22];
    const float* W3   = (const float*)d_in[23];
    const float* b3   = (const float*)d_in[24];
    const float* Wf   = (const float*)d_in[25];
    const float* bf   = (const float*)d_in[26];

    float* out = (float*)d_out;

    // Workspace ping-pong: P0 holds x1 (16x16384x32) then x3 (16x1024x128);
    // P1 holds x2 (16x4096x64) then x4 (16x256x256).
    float* P0 = (float*)d_ws;
    float* P1 = P0 + (size_t)BATCH * 16384 * 32;   // 8.39M floats offset

    // Level 0: x [B,65536,3] -> x1 [B,16384,32]; nnz=49152
    hipMemsetAsync(P0, 0, (size_t)BATCH * 16384 * 32 * sizeof(float), stream);
    conv_pool<3, 32, 8, 4><<<dim3((49152 + 7) / 8, 4), 256, 0, stream>>>(
        x, idx0, row0, col0, val0, W0, b0, P0, 65536, 16384, 49152);

    // Level 1: x1 -> x2 [B,4096,64]; nnz=12288
    hipMemsetAsync(P1, 0, (size_t)BATCH * 4096 * 64 * sizeof(float), stream);
    conv_pool<32, 64, 4, 4><<<dim3((12288 + 3) / 4, 4), 256, 0, stream>>>(
        P0, idx1, row1, col1, val1, W1, b1, P1, 16384, 4096, 12288);

    // Level 2: x2 -> x3 [B,1024,128]; nnz=3072
    hipMemsetAsync(P0, 0, (size_t)BATCH * 1024 * 128 * sizeof(float), stream);
    conv_pool<64, 128, 2, 4><<<dim3((3072 + 1) / 2, 4), 256, 0, stream>>>(
        P1, idx2, row2, col2, val2, W2, b2, P0, 4096, 1024, 3072);

    // Level 3: x3 -> x4 [B,256,256]; nnz=768
    hipMemsetAsync(P1, 0, (size_t)BATCH * 256 * 256 * sizeof(float), stream);
    conv_pool<128, 256, 1, 4><<<dim3(768, 4), 256, 0, stream>>>(
        P0, idx3, row3, col3, val3, W3, b3, P1, 1024, 256, 768);

    // Final: out[16,256] = bf + x4_flat[16,65536] @ Wf[65536,256]
    init_out<<<BATCH, 256, 0, stream>>>(bf, out);
    final_gemm<<<512, 256, 0, stream>>>(P1, Wf, out);
}